// Round 6
// baseline (531.968 us; speedup 1.0000x reference)
//
#include <hip/hip_runtime.h>

#define HH  50    // hidden size
#define RB  16    // batch elements per block (= MFMA N)
#define TT  512   // timesteps
#define FF  4     // input features
#define PA  72    // hA row pitch in u16 (K'=64 + 8 pad, rows 16B-aligned)
#define NW  13    // compute waves (13 tiles x 16 rows >= 200 permuted gate rows)
#define NTH ((NW + 1) * 64)   // 896: waves 0..12 compute, wave 13 streams x

#define L2E 1.4426950408889634f   // log2(e); gate rows pre-scaled by -L2E / -2*L2E

typedef __attribute__((ext_vector_type(8))) short bf16x8;   // 8 bf16 = 4 VGPRs
typedef __attribute__((ext_vector_type(4))) float f32x4;    // MFMA accumulator

__device__ __forceinline__ unsigned short f2bf(float f) {   // RNE fp32->bf16 bits
    unsigned u = __float_as_uint(f);
    u += 0x7FFFu + ((u >> 16) & 1u);
    return (unsigned short)(u >> 16);
}
__device__ __forceinline__ float bf2f(unsigned short s) {
    return __uint_as_float(((unsigned)s) << 16);
}
// single-instr RNE f32->bf16 (low 16 of result). VOP3, no trans hazard.
__device__ __forceinline__ unsigned cvt_pk_bf16(float a, float b) {
    unsigned r;
    asm("v_cvt_pk_bf16_f32 %0, %1, %2" : "=v"(r) : "v"(a), "v"(b));
    return r;
}
// 2^x via compiler-visible intrinsic ONLY (round-4 lesson: v_exp_f32 is a TRANS
// op; the compiler inserts the required hazard wait for builtins but cannot
// see inside opaque inline asm).
__device__ __forceinline__ float exp2_fast(float x) {
#if __has_builtin(__builtin_amdgcn_exp2f)
    return __builtin_amdgcn_exp2f(x);
#else
    return __builtin_exp2f(x);
#endif
}

// raw barrier: drains LDS ops (producer->consumer ordering) but NOT vmcnt --
// wave 13's in-flight x prefetch stays in flight across the barrier.
__device__ __forceinline__ void block_sync_lds() {
    asm volatile("s_waitcnt lgkmcnt(0)\n\ts_barrier" ::: "memory");
}

// split-bf16 W-frag (A operand) for K' elements kb+0..7, row pre-scaled by `scale`.
// K'-layout: [x_hi(0..3) | h_hi(4..53) | x_lo(54..57) | zero(58..63)]
__device__ __forceinline__ void buildB(bf16x8& bh, bf16x8& bl,
    const float* Wx, const float* Wm, int row_o, bool rok, int kb, float scale) {
    #pragma unroll
    for (int ii = 0; ii < 8; ++ii) {
        const int k = kb + ii;
        float wv = 0.0f;
        if (rok) {
            if (k < FF) { if (Wx) wv = Wx[row_o * FF + k]; }
            else if (k < FF + HH) wv = Wm[row_o * HH + (k - FF)];
            else if (k < 2 * FF + HH) { if (Wx) wv = Wx[row_o * FF + (k - FF - HH)]; }
        }
        wv *= scale;
        const unsigned short hb = f2bf(wv);
        bh[ii] = (short)hb;
        bl[ii] = (short)f2bf(wv - bf2f(hb));
    }
}

// LSTM cell in the log2 domain (v14, unchanged). 5 exp2 + 2 rcp.
__device__ __forceinline__ float cell(const f32x4 s, float& cs) {
    const float ei = exp2_fast(s[0]);
    const float ef = exp2_fast(s[1]);
    const float eg = exp2_fast(s[2]);
    const float eo = exp2_fast(s[3]);
    const float ti = 1.0f + ei, tf = 1.0f + ef, tg = 1.0f + eg;
    const float d1 = ti * tg;
    const float r  = __builtin_amdgcn_rcpf(d1 * tf);
    const float sigf = r * d1;                             // sigmoid(f)
    const float g1 = fmaf(2.0f * L2E, eg, -2.0f * L2E);    // -2L*(1-eg)
    const float igs = g1 * (r * tf);                       // -2L*sig(i)*tanh(g)
    cs = fminf(fmaf(sigf, cs, igs), 110.0f);               // cs = -2L*c (overflow-guarded)
    const float ec = exp2_fast(cs);
    const float to = 1.0f + eo, tc = 1.0f + ec;
    const float r2 = __builtin_amdgcn_rcpf(to * tc);
    return (1.0f - ec) * r2;                               // h
}

#define MFMA(a, b, c) __builtin_amdgcn_mfma_f32_16x16x32_bf16(a, b, c, 0, 0, 0)
#define PINB(V) asm volatile("" : "+v"(V));

// ---- per-sub-iter building blocks (addresses are loop-invariant registers) ----
#define LOAD_A(RA0, RA1) \
    const bf16x8 A0 = *(const bf16x8*)(RA0); \
    const bf16x8 A1 = *(const bf16x8*)((RA0) + 32); \
    const bf16x8 A4 = *(const bf16x8*)(RA1); \
    const bf16x8 A5 = *(const bf16x8*)((RA1) + 32);

#define L0_BLOCK(WH0) do { \
    f32x4 a_ = C0; \
    a_ = MFMA(B0h0, A0, a_); a_ = MFMA(B0h1, A1, a_); \
    a_ = MFMA(B0l0, A0, a_); a_ = MFMA(B0l1, A1, a_); \
    if (uvalid) { \
        const float h_ = cell(a_, c0); \
        *(WH0) = (unsigned short)cvt_pk_bf16(h_, h_); \
    } \
} while (0)

#define L1_BLOCK(WH1) do { \
    f32x4 p_ = C1, q_ = Z0; \
    p_ = MFMA(B1h0, A0, p_); p_ = MFMA(B1h1, A1, p_); \
    p_ = MFMA(B1l0, A0, p_); p_ = MFMA(B1l1, A1, p_); \
    q_ = MFMA(B2h0, A4, q_); q_ = MFMA(B2h1, A5, q_); \
    q_ = MFMA(B2l0, A4, q_); q_ = MFMA(B2l1, A5, q_); \
    if (uvalid) { \
        const float h_ = cell(p_ + q_, c1); \
        *(WH1) = (unsigned short)cvt_pk_bf16(h_, h_); \
    } \
} while (0)

// compute sub-iter: read parity buffers RA*, write opposite-parity WH*.
// swapord waves run L1 first -> per-SIMD staggered trans/MFMA bursts.
#define CSTEP(RA0, RA1, WH0, WH1, DO_L1) do { \
    LOAD_A(RA0, RA1) \
    if (swapord) { if (DO_L1) L1_BLOCK(WH1); L0_BLOCK(WH0); } \
    else         { L0_BLOCK(WH0); if (DO_L1) L1_BLOCK(WH1); } \
} while (0)

__attribute__((amdgpu_waves_per_eu(4, 4)))
__launch_bounds__(NTH)
__global__ void lstm_v15(const float* __restrict__ x,
                         const float* __restrict__ Wih0, const float* __restrict__ Whh0,
                         const float* __restrict__ bih0, const float* __restrict__ bhh0,
                         const float* __restrict__ Wih1, const float* __restrict__ Whh1,
                         const float* __restrict__ bih1, const float* __restrict__ bhh1,
                         const float* __restrict__ fcW,  const float* __restrict__ fcb,
                         float* __restrict__ out)
{
    // ping-pong h buffers; h stored bf16 (single plane), x stored bf16 hi+lo
    __shared__ __align__(16) unsigned short hA0[2][16 * PA];
    __shared__ __align__(16) unsigned short hA1[2][16 * PA];
    __shared__ float h1f[HH * 16];     // final h1 fp32 for FC

    const int tid  = threadIdx.x;
    const int w    = tid >> 6;
    const int lane = tid & 63;
    const int b0   = blockIdx.x * RB;

    const int n15 = lane & 15;
    const int qk  = lane >> 4;
    const int qk8 = qk * 8;

    // D = W . h^T  =>  lane holds D[row'=qk*4+reg][batch=n15]
    const int m = n15;                    // ew batch
    const int u = w * 4 + qk;             // ew unit
    const bool uvalid = (w < NW) && (u < HH);
    const int um = uvalid ? u : 0;

    // W-frag row (A operand M index): permuted row' = w*16 + n15
    const int rowp  = w * 16 + n15;
    const int gidx  = rowp & 3;
    const int runit = rowp >> 2;
    const bool rok  = (w < NW) && (runit < HH);
    const int row_o = rok ? gidx * HH + runit : 0;     // original row g*50+unit
    const float wscale = (gidx == 2) ? (-2.0f * L2E) : (-L2E);   // g-gate rows x2

    // per-SIMD phase stagger: waves s,s+4,s+8,s+12 live on SIMD s, so key on w>>2
    const bool swapord = ((w >> 2) & 1) != 0;

    for (int idx = tid; idx < 16 * PA; idx += NTH) {
        hA0[0][idx] = 0; hA0[1][idx] = 0;
        hA1[0][idx] = 0; hA1[1][idx] = 0;
    }

    // ---- W-frags: 12 register-resident split-bf16 fragments (pre-scaled) ----
    bf16x8 B0h0, B0h1, B0l0, B0l1, B1h0, B1h1, B1l0, B1l1, B2h0, B2h1, B2l0, B2l1;
    buildB(B0h0, B0l0, Wih0, Whh0, row_o, rok, qk8, wscale);        // L0: [Wih0 | Whh0]
    buildB(B0h1, B0l1, Wih0, Whh0, row_o, rok, 32 + qk8, wscale);
    buildB(B1h0, B1l0, nullptr, Wih1, row_o, rok, qk8, wscale);     // L1-ih (vs h0)
    buildB(B1h1, B1l1, nullptr, Wih1, row_o, rok, 32 + qk8, wscale);
    buildB(B2h0, B2l0, nullptr, Whh1, row_o, rok, qk8, wscale);     // L1-hh (vs h1)
    buildB(B2h1, B2l1, nullptr, Whh1, row_o, rok, 32 + qk8, wscale);
    PINB(B0h0) PINB(B0h1) PINB(B0l0) PINB(B0l1)
    PINB(B1h0) PINB(B1h1) PINB(B1l0) PINB(B1l1)
    PINB(B2h0) PINB(B2h1) PINB(B2l0) PINB(B2l1)

    // bias vectors preloaded into the MFMA C operand, log2-domain scaled
    const f32x4 C0 = {-L2E        * (bih0[0*HH + um] + bhh0[0*HH + um]),
                      -L2E        * (bih0[1*HH + um] + bhh0[1*HH + um]),
                      -2.0f * L2E * (bih0[2*HH + um] + bhh0[2*HH + um]),
                      -L2E        * (bih0[3*HH + um] + bhh0[3*HH + um])};
    const f32x4 C1 = {-L2E        * (bih1[0*HH + um] + bhh1[0*HH + um]),
                      -L2E        * (bih1[1*HH + um] + bhh1[1*HH + um]),
                      -2.0f * L2E * (bih1[2*HH + um] + bhh1[2*HH + um]),
                      -L2E        * (bih1[3*HH + um] + bhh1[3*HH + um])};
    const f32x4 Z0 = {0.f, 0.f, 0.f, 0.f};   // loop-invariant zero seed

    // ---- loop-invariant LDS addresses (unrolled x2 -> parities hard-coded) ----
    const int ab = n15 * PA + qk8;
    const unsigned short* ra00 = &hA0[0][ab];
    const unsigned short* ra01 = &hA0[1][ab];
    const unsigned short* ra10 = &hA1[0][ab];
    const unsigned short* ra11 = &hA1[1][ab];
    const int wo = m * PA + 4 + u;
    unsigned short* wh00 = &hA0[0][wo];
    unsigned short* wh01 = &hA0[1][wo];
    unsigned short* wh10 = &hA1[0][wo];
    unsigned short* wh11 = &hA1[1][wo];

    // wave-13 x prefetch registers (2-iter latency slack; vm never drains at barrier)
    const int xm = lane >> 2, xk = lane & 3;
    unsigned short* xw0 = &hA0[0][xm * PA + xk];
    unsigned short* xw1 = &hA0[1][xm * PA + xk];
    float xcur = 0.f, xnxt = 0.f;
    if (w == NW) {
        xcur = x[((size_t)(b0 + xm) * TT + 1) * FF + xk];
        xnxt = x[((size_t)(b0 + xm) * TT + 2) * FF + xk];
    }

    __syncthreads();

    // x(0) into parity-0 buffer (hi + lo planes)
    if (w == 0) {
        const float xv = x[((size_t)(b0 + xm) * TT + 0) * FF + xk];
        const unsigned short hb = f2bf(xv);
        hA0[0][xm * PA + xk]      = hb;
        hA0[0][xm * PA + 54 + xk] = f2bf(xv - bf2f(hb));
    }
    __syncthreads();

    float c0 = 0.f, c1 = 0.f;   // carried as cs = -2*L2E*c

    // pair loop: sub-iter A = timestep i (parity 0), sub-iter B = i+1 (parity 1)
    for (int i = 0; i < TT; i += 2) {
        if (w < NW) {
            CSTEP(ra00, ra10, wh01, wh11, (i > 0));
        } else {
            // sub-A: issue x(i+3), publish x(i+1) -> parity-1 buffer
            float xn1 = 0.f;
            if (i + 3 < TT) xn1 = x[((size_t)(b0 + xm) * TT + (i + 3)) * FF + xk];
            const unsigned short hb = f2bf(xcur);       // x(i+1): i+1 <= 511 always
            xw1[0]  = hb;
            xw1[54] = f2bf(xcur - bf2f(hb));
            xcur = xn1;                                  // becomes x((i+2)+1)
        }
        block_sync_lds();

        if (w < NW) {
            CSTEP(ra01, ra11, wh00, wh10, true);
        } else {
            // sub-B: issue x(i+4), publish x(i+2) -> parity-0 buffer
            float xn2 = 0.f;
            if (i + 4 < TT) xn2 = x[((size_t)(b0 + xm) * TT + (i + 4)) * FF + xk];
            if (i + 2 < TT) {
                const unsigned short hb = f2bf(xnxt);
                xw0[0]  = hb;
                xw0[54] = f2bf(xnxt - bf2f(hb));
            }
            xnxt = xn2;                                  // becomes x((i+2)+2)
        }
        block_sync_lds();
    }

    // tail: timestep TT (parity 0 read) -- L1 only, result goes to h1f
    if (w < NW) {
        const bf16x8 A0 = *(const bf16x8*)(ra00);
        const bf16x8 A1 = *(const bf16x8*)(ra00 + 32);
        const bf16x8 A4 = *(const bf16x8*)(ra10);
        const bf16x8 A5 = *(const bf16x8*)(ra10 + 32);
        f32x4 p = C1, q = Z0;
        p = MFMA(B1h0, A0, p); p = MFMA(B1h1, A1, p);
        p = MFMA(B1l0, A0, p); p = MFMA(B1l1, A1, p);
        q = MFMA(B2h0, A4, q); q = MFMA(B2h1, A5, q);
        q = MFMA(B2l0, A4, q); q = MFMA(B2l1, A5, q);
        if (uvalid) {
            const float h = cell(p + q, c1);
            h1f[u * 16 + m] = h;
        }
    }
    __syncthreads();

    // ---- final FC: out[b] = fcW @ h1(T-1) + fcb ----
    if (tid < RB * FF) {
        const int r = tid >> 2, ft = tid & 3;
        float s = fcb[ft];
        #pragma unroll
        for (int j = 0; j < HH; j++) s = fmaf(fcW[ft * HH + j], h1f[j * 16 + r], s);
        out[(size_t)(b0 + r) * FF + ft] = s;
    }
}

extern "C" void kernel_launch(void* const* d_in, const int* in_sizes, int n_in,
                              void* d_out, int out_size, void* d_ws, size_t ws_size,
                              hipStream_t stream) {
    const float* x    = (const float*)d_in[0];
    const float* Wih0 = (const float*)d_in[1];
    const float* Whh0 = (const float*)d_in[2];
    const float* bih0 = (const float*)d_in[3];
    const float* bhh0 = (const float*)d_in[4];
    const float* Wih1 = (const float*)d_in[5];
    const float* Whh1 = (const float*)d_in[6];
    const float* bih1 = (const float*)d_in[7];
    const float* bhh1 = (const float*)d_in[8];
    const float* fcW  = (const float*)d_in[9];
    const float* fcb  = (const float*)d_in[10];
    float* out = (float*)d_out;

    const int B = in_sizes[0] / (TT * FF);   // 4096
    lstm_v15<<<B / RB, NTH, 0, stream>>>(x, Wih0, Whh0, bih0, bhh0,
                                         Wih1, Whh1, bih1, bhh1, fcW, fcb, out);
}

// Round 7
// 489.846 us; speedup vs baseline: 1.0860x; 1.0860x over previous
//
#include <hip/hip_runtime.h>

#define HH  50    // hidden size
#define RB  16    // batch elements per block (= MFMA N)
#define TT  512   // timesteps
#define FF  4     // input features
#define PA  72    // hA row pitch in u16 (K'=64 + 8 pad, rows 16B-aligned)
#define NW  13    // compute waves (13 tiles x 16 rows >= 200 permuted gate rows)
#define NTH ((NW + 1) * 64)   // 896: waves 0..12 compute, wave 13 streams x

#define L2E 1.4426950408889634f   // log2(e); gate rows pre-scaled by -L2E / -2*L2E

typedef __attribute__((ext_vector_type(8))) short bf16x8;   // 8 bf16 = 4 VGPRs
typedef __attribute__((ext_vector_type(4))) float f32x4;    // MFMA accumulator

__device__ __forceinline__ unsigned short f2bf(float f) {   // RNE fp32->bf16 bits
    unsigned u = __float_as_uint(f);
    u += 0x7FFFu + ((u >> 16) & 1u);
    return (unsigned short)(u >> 16);
}
__device__ __forceinline__ float bf2f(unsigned short s) {
    return __uint_as_float(((unsigned)s) << 16);
}
// single-instr RNE f32->bf16 (low 16 of result). VOP3, no trans hazard.
__device__ __forceinline__ unsigned cvt_pk_bf16(float a, float b) {
    unsigned r;
    asm("v_cvt_pk_bf16_f32 %0, %1, %2" : "=v"(r) : "v"(a), "v"(b));
    return r;
}
// 2^x via compiler-visible intrinsic ONLY (round-4 lesson: v_exp_f32 is a TRANS
// op; the compiler inserts the required hazard wait for builtins but cannot
// see inside opaque inline asm).
__device__ __forceinline__ float exp2_fast(float x) {
#if __has_builtin(__builtin_amdgcn_exp2f)
    return __builtin_amdgcn_exp2f(x);
#else
    return __builtin_exp2f(x);
#endif
}

// raw barrier: drains LDS ops (producer->consumer ordering) but NOT vmcnt --
// wave 13's in-flight x prefetch stays in flight across the barrier.
__device__ __forceinline__ void block_sync_lds() {
    asm volatile("s_waitcnt lgkmcnt(0)\n\ts_barrier" ::: "memory");
}

// split-bf16 W-frag (A operand) for K' elements kb+0..7, row pre-scaled by `scale`.
// K'-layout: [x_hi(0..3) | h_hi(4..53) | x_lo(54..57) | zero(58..63)]
__device__ __forceinline__ void buildB(bf16x8& bh, bf16x8& bl,
    const float* Wx, const float* Wm, int row_o, bool rok, int kb, float scale) {
    #pragma unroll
    for (int ii = 0; ii < 8; ++ii) {
        const int k = kb + ii;
        float wv = 0.0f;
        if (rok) {
            if (k < FF) { if (Wx) wv = Wx[row_o * FF + k]; }
            else if (k < FF + HH) wv = Wm[row_o * HH + (k - FF)];
            else if (k < 2 * FF + HH) { if (Wx) wv = Wx[row_o * FF + (k - FF - HH)]; }
        }
        wv *= scale;
        const unsigned short hb = f2bf(wv);
        bh[ii] = (short)hb;
        bl[ii] = (short)f2bf(wv - bf2f(hb));
    }
}

// LSTM cell in the log2 domain (v14, unchanged). 5 exp2 + 2 rcp.
__device__ __forceinline__ float cell(const f32x4 s, float& cs) {
    const float ei = exp2_fast(s[0]);
    const float ef = exp2_fast(s[1]);
    const float eg = exp2_fast(s[2]);
    const float eo = exp2_fast(s[3]);
    const float ti = 1.0f + ei, tf = 1.0f + ef, tg = 1.0f + eg;
    const float d1 = ti * tg;
    const float r  = __builtin_amdgcn_rcpf(d1 * tf);
    const float sigf = r * d1;                             // sigmoid(f)
    const float g1 = fmaf(2.0f * L2E, eg, -2.0f * L2E);    // -2L*(1-eg)
    const float igs = g1 * (r * tf);                       // -2L*sig(i)*tanh(g)
    cs = fminf(fmaf(sigf, cs, igs), 110.0f);               // cs = -2L*c (overflow-guarded)
    const float ec = exp2_fast(cs);
    const float to = 1.0f + eo, tc = 1.0f + ec;
    const float r2 = __builtin_amdgcn_rcpf(to * tc);
    return (1.0f - ec) * r2;                               // h
}

#define MFMA(a, b, c) __builtin_amdgcn_mfma_f32_16x16x32_bf16(a, b, c, 0, 0, 0)
#define PINB(V) asm volatile("" : "+v"(V));

// ---- per-sub-iter building blocks (addresses are loop-invariant registers) ----
#define LOAD_A(RA0, RA1) \
    const bf16x8 A0 = *(const bf16x8*)(RA0); \
    const bf16x8 A1 = *(const bf16x8*)((RA0) + 32); \
    const bf16x8 A4 = *(const bf16x8*)(RA1); \
    const bf16x8 A5 = *(const bf16x8*)((RA1) + 32);

#define L0_BLOCK(WH0) do { \
    f32x4 a_ = C0; \
    a_ = MFMA(B0h0, A0, a_); a_ = MFMA(B0h1, A1, a_); \
    a_ = MFMA(B0l0, A0, a_); a_ = MFMA(B0l1, A1, a_); \
    if (uvalid) { \
        const float h_ = cell(a_, c0); \
        *(WH0) = (unsigned short)cvt_pk_bf16(h_, h_); \
    } \
} while (0)

#define L1_BLOCK(WH1) do { \
    f32x4 p_ = C1, q_ = Z0; \
    p_ = MFMA(B1h0, A0, p_); p_ = MFMA(B1h1, A1, p_); \
    p_ = MFMA(B1l0, A0, p_); p_ = MFMA(B1l1, A1, p_); \
    q_ = MFMA(B2h0, A4, q_); q_ = MFMA(B2h1, A5, q_); \
    q_ = MFMA(B2l0, A4, q_); q_ = MFMA(B2l1, A5, q_); \
    if (uvalid) { \
        const float h_ = cell(p_ + q_, c1); \
        *(WH1) = (unsigned short)cvt_pk_bf16(h_, h_); \
    } \
} while (0)

// compute sub-iter: read parity buffers RA*, write opposite-parity WH*.
// uniform L0->L1 order for all waves (v15's per-SIMD swapord stagger REGRESSED:
// diverging instruction streams de-phased the natural cross-wave pipe overlap).
#define CSTEP(RA0, RA1, WH0, WH1, DO_L1) do { \
    LOAD_A(RA0, RA1) \
    L0_BLOCK(WH0); \
    if (DO_L1) L1_BLOCK(WH1); \
} while (0)

__attribute__((amdgpu_waves_per_eu(4, 4)))
__launch_bounds__(NTH)
__global__ void lstm_v16(const float* __restrict__ x,
                         const float* __restrict__ Wih0, const float* __restrict__ Whh0,
                         const float* __restrict__ bih0, const float* __restrict__ bhh0,
                         const float* __restrict__ Wih1, const float* __restrict__ Whh1,
                         const float* __restrict__ bih1, const float* __restrict__ bhh1,
                         const float* __restrict__ fcW,  const float* __restrict__ fcb,
                         float* __restrict__ out)
{
    // ping-pong h buffers; h stored bf16 (single plane), x stored bf16 hi+lo
    __shared__ __align__(16) unsigned short hA0[2][16 * PA];
    __shared__ __align__(16) unsigned short hA1[2][16 * PA];
    __shared__ float h1f[HH * 16];     // final h1 fp32 for FC

    const int tid  = threadIdx.x;
    const int w    = tid >> 6;
    const int lane = tid & 63;
    const int b0   = blockIdx.x * RB;

    const int n15 = lane & 15;
    const int qk  = lane >> 4;
    const int qk8 = qk * 8;

    // D = W . h^T  =>  lane holds D[row'=qk*4+reg][batch=n15]
    const int m = n15;                    // ew batch
    const int u = w * 4 + qk;             // ew unit
    const bool uvalid = (w < NW) && (u < HH);
    const int um = uvalid ? u : 0;

    // W-frag row (A operand M index): permuted row' = w*16 + n15
    const int rowp  = w * 16 + n15;
    const int gidx  = rowp & 3;
    const int runit = rowp >> 2;
    const bool rok  = (w < NW) && (runit < HH);
    const int row_o = rok ? gidx * HH + runit : 0;     // original row g*50+unit
    const float wscale = (gidx == 2) ? (-2.0f * L2E) : (-L2E);   // g-gate rows x2

    for (int idx = tid; idx < 16 * PA; idx += NTH) {
        hA0[0][idx] = 0; hA0[1][idx] = 0;
        hA1[0][idx] = 0; hA1[1][idx] = 0;
    }

    // ---- W-frags: 12 register-resident split-bf16 fragments (pre-scaled) ----
    bf16x8 B0h0, B0h1, B0l0, B0l1, B1h0, B1h1, B1l0, B1l1, B2h0, B2h1, B2l0, B2l1;
    buildB(B0h0, B0l0, Wih0, Whh0, row_o, rok, qk8, wscale);        // L0: [Wih0 | Whh0]
    buildB(B0h1, B0l1, Wih0, Whh0, row_o, rok, 32 + qk8, wscale);
    buildB(B1h0, B1l0, nullptr, Wih1, row_o, rok, qk8, wscale);     // L1-ih (vs h0)
    buildB(B1h1, B1l1, nullptr, Wih1, row_o, rok, 32 + qk8, wscale);
    buildB(B2h0, B2l0, nullptr, Whh1, row_o, rok, qk8, wscale);     // L1-hh (vs h1)
    buildB(B2h1, B2l1, nullptr, Whh1, row_o, rok, 32 + qk8, wscale);
    PINB(B0h0) PINB(B0h1) PINB(B0l0) PINB(B0l1)
    PINB(B1h0) PINB(B1h1) PINB(B1l0) PINB(B1l1)
    PINB(B2h0) PINB(B2h1) PINB(B2l0) PINB(B2l1)

    // bias vectors preloaded into the MFMA C operand, log2-domain scaled
    const f32x4 C0 = {-L2E        * (bih0[0*HH + um] + bhh0[0*HH + um]),
                      -L2E        * (bih0[1*HH + um] + bhh0[1*HH + um]),
                      -2.0f * L2E * (bih0[2*HH + um] + bhh0[2*HH + um]),
                      -L2E        * (bih0[3*HH + um] + bhh0[3*HH + um])};
    const f32x4 C1 = {-L2E        * (bih1[0*HH + um] + bhh1[0*HH + um]),
                      -L2E        * (bih1[1*HH + um] + bhh1[1*HH + um]),
                      -2.0f * L2E * (bih1[2*HH + um] + bhh1[2*HH + um]),
                      -L2E        * (bih1[3*HH + um] + bhh1[3*HH + um])};
    const f32x4 Z0 = {0.f, 0.f, 0.f, 0.f};   // loop-invariant zero seed

    // ---- loop-invariant LDS addresses (unrolled x2 -> parities hard-coded) ----
    const int ab = n15 * PA + qk8;
    const unsigned short* ra00 = &hA0[0][ab];
    const unsigned short* ra01 = &hA0[1][ab];
    const unsigned short* ra10 = &hA1[0][ab];
    const unsigned short* ra11 = &hA1[1][ab];
    const int wo = m * PA + 4 + u;
    unsigned short* wh00 = &hA0[0][wo];
    unsigned short* wh01 = &hA0[1][wo];
    unsigned short* wh10 = &hA1[0][wo];
    unsigned short* wh11 = &hA1[1][wo];

    // wave-13 x prefetch registers (2-iter latency slack; vm never drains at barrier)
    const int xm = lane >> 2, xk = lane & 3;
    unsigned short* xw0 = &hA0[0][xm * PA + xk];
    unsigned short* xw1 = &hA0[1][xm * PA + xk];
    float xcur = 0.f, xnxt = 0.f;
    if (w == NW) {
        xcur = x[((size_t)(b0 + xm) * TT + 1) * FF + xk];
        xnxt = x[((size_t)(b0 + xm) * TT + 2) * FF + xk];
    }

    __syncthreads();

    // x(0) into parity-0 buffer (hi + lo planes)
    if (w == 0) {
        const float xv = x[((size_t)(b0 + xm) * TT + 0) * FF + xk];
        const unsigned short hb = f2bf(xv);
        hA0[0][xm * PA + xk]      = hb;
        hA0[0][xm * PA + 54 + xk] = f2bf(xv - bf2f(hb));
    }
    __syncthreads();

    float c0 = 0.f, c1 = 0.f;   // carried as cs = -2*L2E*c

    // pair loop: sub-iter A = timestep i (parity 0), sub-iter B = i+1 (parity 1)
    for (int i = 0; i < TT; i += 2) {
        if (w < NW) {
            CSTEP(ra00, ra10, wh01, wh11, (i > 0));
        } else {
            // sub-A: issue x(i+3), publish x(i+1) -> parity-1 buffer
            float xn1 = 0.f;
            if (i + 3 < TT) xn1 = x[((size_t)(b0 + xm) * TT + (i + 3)) * FF + xk];
            const unsigned short hb = f2bf(xcur);       // x(i+1): i+1 <= 511 always
            xw1[0]  = hb;
            xw1[54] = f2bf(xcur - bf2f(hb));
            xcur = xn1;                                  // becomes x((i+2)+1)
        }
        block_sync_lds();

        if (w < NW) {
            CSTEP(ra01, ra11, wh00, wh10, true);
        } else {
            // sub-B: issue x(i+4), publish x(i+2) -> parity-0 buffer
            float xn2 = 0.f;
            if (i + 4 < TT) xn2 = x[((size_t)(b0 + xm) * TT + (i + 4)) * FF + xk];
            if (i + 2 < TT) {
                const unsigned short hb = f2bf(xnxt);
                xw0[0]  = hb;
                xw0[54] = f2bf(xnxt - bf2f(hb));
            }
            xnxt = xn2;                                  // becomes x((i+2)+2)
        }
        block_sync_lds();
    }

    // tail: timestep TT (parity 0 read) -- L1 only, result goes to h1f
    if (w < NW) {
        const bf16x8 A0 = *(const bf16x8*)(ra00);
        const bf16x8 A1 = *(const bf16x8*)(ra00 + 32);
        const bf16x8 A4 = *(const bf16x8*)(ra10);
        const bf16x8 A5 = *(const bf16x8*)(ra10 + 32);
        f32x4 p = C1, q = Z0;
        p = MFMA(B1h0, A0, p); p = MFMA(B1h1, A1, p);
        p = MFMA(B1l0, A0, p); p = MFMA(B1l1, A1, p);
        q = MFMA(B2h0, A4, q); q = MFMA(B2h1, A5, q);
        q = MFMA(B2l0, A4, q); q = MFMA(B2l1, A5, q);
        if (uvalid) {
            const float h = cell(p + q, c1);
            h1f[u * 16 + m] = h;
        }
    }
    __syncthreads();

    // ---- final FC: out[b] = fcW @ h1(T-1) + fcb ----
    if (tid < RB * FF) {
        const int r = tid >> 2, ft = tid & 3;
        float s = fcb[ft];
        #pragma unroll
        for (int j = 0; j < HH; j++) s = fmaf(fcW[ft * HH + j], h1f[j * 16 + r], s);
        out[(size_t)(b0 + r) * FF + ft] = s;
    }
}

extern "C" void kernel_launch(void* const* d_in, const int* in_sizes, int n_in,
                              void* d_out, int out_size, void* d_ws, size_t ws_size,
                              hipStream_t stream) {
    const float* x    = (const float*)d_in[0];
    const float* Wih0 = (const float*)d_in[1];
    const float* Whh0 = (const float*)d_in[2];
    const float* bih0 = (const float*)d_in[3];
    const float* bhh0 = (const float*)d_in[4];
    const float* Wih1 = (const float*)d_in[5];
    const float* Whh1 = (const float*)d_in[6];
    const float* bih1 = (const float*)d_in[7];
    const float* bhh1 = (const float*)d_in[8];
    const float* fcW  = (const float*)d_in[9];
    const float* fcb  = (const float*)d_in[10];
    float* out = (float*)d_out;

    const int B = in_sizes[0] / (TT * FF);   // 4096
    lstm_v16<<<B / RB, NTH, 0, stream>>>(x, Wih0, Whh0, bih0, bhh0,
                                         Wih1, Whh1, bih1, bhh1, fcW, fcb, out);
}

// Round 8
// 458.118 us; speedup vs baseline: 1.1612x; 1.0693x over previous
//
#include <hip/hip_runtime.h>

#define HH  50    // hidden size
#define RB  16    // batch elements per block (= MFMA N)
#define TT  512   // timesteps
#define FF  4     // input features
#define PA  72    // hA row pitch in u16 (K'=64 + 8 pad, rows 16B-aligned)
#define NW  13    // compute tiles (13 x 16 rows >= 200 permuted gate rows)
#define NTH ((NW + 1) * 64)   // 896 threads, 14 waves

#define L2E 1.4426950408889634f   // log2(e); gate rows pre-scaled by -L2E / -2*L2E

typedef __attribute__((ext_vector_type(8))) short bf16x8;   // 8 bf16 = 4 VGPRs
typedef __attribute__((ext_vector_type(4))) float f32x4;    // MFMA accumulator

__device__ __forceinline__ unsigned short f2bf(float f) {   // RNE fp32->bf16 bits
    unsigned u = __float_as_uint(f);
    u += 0x7FFFu + ((u >> 16) & 1u);
    return (unsigned short)(u >> 16);
}
__device__ __forceinline__ float bf2f(unsigned short s) {
    return __uint_as_float(((unsigned)s) << 16);
}
// single-instr RNE f32->bf16 (low 16 of result). VOP3, no trans hazard.
__device__ __forceinline__ unsigned cvt_pk_bf16(float a, float b) {
    unsigned r;
    asm("v_cvt_pk_bf16_f32 %0, %1, %2" : "=v"(r) : "v"(a), "v"(b));
    return r;
}
// 2^x via compiler-visible intrinsic ONLY (round-4 lesson: v_exp_f32 is a TRANS
// op; the compiler inserts the required hazard wait for builtins but cannot
// see inside opaque inline asm).
__device__ __forceinline__ float exp2_fast(float x) {
#if __has_builtin(__builtin_amdgcn_exp2f)
    return __builtin_amdgcn_exp2f(x);
#else
    return __builtin_exp2f(x);
#endif
}

// raw barrier: drains LDS ops (producer->consumer ordering) but NOT vmcnt --
// the x-wave's in-flight prefetch stays in flight across the barrier.
__device__ __forceinline__ void block_sync_lds() {
    asm volatile("s_waitcnt lgkmcnt(0)\n\ts_barrier" ::: "memory");
}

// split-bf16 W-frag (A operand) for K' elements kb+0..7, row pre-scaled by `scale`.
// K'-layout: [x_hi(0..3) | h_hi(4..53) | x_lo(54..57) | zero(58..63)]
__device__ __forceinline__ void buildB(bf16x8& bh, bf16x8& bl,
    const float* Wx, const float* Wm, int row_o, bool rok, int kb, float scale) {
    #pragma unroll
    for (int ii = 0; ii < 8; ++ii) {
        const int k = kb + ii;
        float wv = 0.0f;
        if (rok) {
            if (k < FF) { if (Wx) wv = Wx[row_o * FF + k]; }
            else if (k < FF + HH) wv = Wm[row_o * HH + (k - FF)];
            else if (k < 2 * FF + HH) { if (Wx) wv = Wx[row_o * FF + (k - FF - HH)]; }
        }
        wv *= scale;
        const unsigned short hb = f2bf(wv);
        bh[ii] = (short)hb;
        bl[ii] = (short)f2bf(wv - bf2f(hb));
    }
}

// LSTM cell in the log2 domain (v14, unchanged). 5 exp2 + 2 rcp.
__device__ __forceinline__ float cell(const f32x4 s, float& cs) {
    const float ei = exp2_fast(s[0]);
    const float ef = exp2_fast(s[1]);
    const float eg = exp2_fast(s[2]);
    const float eo = exp2_fast(s[3]);
    const float ti = 1.0f + ei, tf = 1.0f + ef, tg = 1.0f + eg;
    const float d1 = ti * tg;
    const float r  = __builtin_amdgcn_rcpf(d1 * tf);
    const float sigf = r * d1;                             // sigmoid(f)
    const float g1 = fmaf(2.0f * L2E, eg, -2.0f * L2E);    // -2L*(1-eg)
    const float igs = g1 * (r * tf);                       // -2L*sig(i)*tanh(g)
    cs = fminf(fmaf(sigf, cs, igs), 110.0f);               // cs = -2L*c (overflow-guarded)
    const float ec = exp2_fast(cs);
    const float to = 1.0f + eo, tc = 1.0f + ec;
    const float r2 = __builtin_amdgcn_rcpf(to * tc);
    return (1.0f - ec) * r2;                               // h
}

#define MFMA(a, b, c) __builtin_amdgcn_mfma_f32_16x16x32_bf16(a, b, c, 0, 0, 0)
#define PINB(V) asm volatile("" : "+v"(V));

// L0 job: 4-MFMA chain + cell on (u0, c0), writes h0 row
#define L0_BLOCK(WH0) do { \
    f32x4 a_ = C0; \
    a_ = MFMA(B0h0, A0, a_); a_ = MFMA(B0h1, A1, a_); \
    a_ = MFMA(B0l0, A0, a_); a_ = MFMA(B0l1, A1, a_); \
    if (uvalid0) { \
        const float h_ = cell(a_, c0); \
        *(WH0) = (unsigned short)cvt_pk_bf16(h_, h_); \
    } \
} while (0)

// L1 job: two 4-MFMA chains + cell on (u1, c1), writes h1 row
#define L1_BLOCK(WH1) do { \
    f32x4 p_ = C1, q_ = Z0; \
    p_ = MFMA(B1h0, A0, p_); p_ = MFMA(B1h1, A1, p_); \
    p_ = MFMA(B1l0, A0, p_); p_ = MFMA(B1l1, A1, p_); \
    q_ = MFMA(B2h0, A4, q_); q_ = MFMA(B2h1, A5, q_); \
    q_ = MFMA(B2l0, A4, q_); q_ = MFMA(B2l1, A5, q_); \
    if (uvalid1) { \
        const float h_ = cell(p_ + q_, c1); \
        *(WH1) = (unsigned short)cvt_pk_bf16(h_, h_); \
    } \
} while (0)

// sub-iter: read parity RA*, write opposite parity WH*. Role flags select jobs.
// SIMD balance (w%4 placement): waves 0-11 = L0+L1(own tile); wave 12 (hot
// SIMD0) = L0 of tile 12 ONLY; wave 13 (SIMD1) = x-stream + L1 of tile 12.
#define CSTEP(RA0, RA1, WH0, WH1, DO_L1_NOW) do { \
    const bf16x8 A0 = *(const bf16x8*)(RA0); \
    const bf16x8 A1 = *(const bf16x8*)((RA0) + 32); \
    if (doL0) L0_BLOCK(WH0); \
    if (doL1 && (DO_L1_NOW)) { \
        const bf16x8 A4 = *(const bf16x8*)(RA1); \
        const bf16x8 A5 = *(const bf16x8*)((RA1) + 32); \
        L1_BLOCK(WH1); \
    } \
} while (0)

__attribute__((amdgpu_waves_per_eu(4, 4)))
__launch_bounds__(NTH)
__global__ void lstm_v17(const float* __restrict__ x,
                         const float* __restrict__ Wih0, const float* __restrict__ Whh0,
                         const float* __restrict__ bih0, const float* __restrict__ bhh0,
                         const float* __restrict__ Wih1, const float* __restrict__ Whh1,
                         const float* __restrict__ bih1, const float* __restrict__ bhh1,
                         const float* __restrict__ fcW,  const float* __restrict__ fcb,
                         float* __restrict__ out)
{
    // ping-pong h buffers; h stored bf16 (single plane), x stored bf16 hi+lo
    __shared__ __align__(16) unsigned short hA0[2][16 * PA];
    __shared__ __align__(16) unsigned short hA1[2][16 * PA];
    __shared__ float h1f[HH * 16];     // final h1 fp32 for FC

    const int tid  = threadIdx.x;
    const int w    = tid >> 6;
    const int lane = tid & 63;
    const int b0   = blockIdx.x * RB;

    const int n15 = lane & 15;
    const int qk  = lane >> 4;
    const int qk8 = qk * 8;
    const int m   = n15;                  // ew batch

    // ---- per-wave roles ----
    const bool isX  = (w == NW);           // wave 13: x-stream + L1 of tile 12
    const bool doL0 = (w <= 12);           // L0 of tile w
    const bool doL1 = (w <= 11) || isX;    // L1 of tile (isX ? 12 : w)
    const int  tl1  = isX ? 12 : w;

    // ew units: L0 on (u0,c0), L1 on (u1,c1)
    const int u0 = w * 4 + qk;
    const int u1 = tl1 * 4 + qk;
    const bool uvalid0 = doL0 && (u0 < HH);
    const bool uvalid1 = doL1 && (u1 < HH);
    const int um0 = uvalid0 ? u0 : 0;
    const int um1 = uvalid1 ? u1 : 0;

    // W-frag rows (A operand M index): permuted row' = tile*16 + n15
    const int rowp0  = w * 16 + n15;
    const int rowp1  = tl1 * 16 + n15;
    const int runit0 = rowp0 >> 2, runit1 = rowp1 >> 2;
    const bool rok0  = doL0 && (runit0 < HH);
    const bool rok1  = doL1 && (runit1 < HH);
    const int row_o0 = rok0 ? (rowp0 & 3) * HH + runit0 : 0;
    const int row_o1 = rok1 ? (rowp1 & 3) * HH + runit1 : 0;
    const float wscale0 = ((rowp0 & 3) == 2) ? (-2.0f * L2E) : (-L2E);
    const float wscale1 = ((rowp1 & 3) == 2) ? (-2.0f * L2E) : (-L2E);

    for (int idx = tid; idx < 16 * PA; idx += NTH) {
        hA0[0][idx] = 0; hA0[1][idx] = 0;
        hA1[0][idx] = 0; hA1[1][idx] = 0;
    }

    // ---- W-frags: split-bf16, pre-scaled. Unused frags are zero (rok=false). ----
    bf16x8 B0h0, B0h1, B0l0, B0l1, B1h0, B1h1, B1l0, B1l1, B2h0, B2h1, B2l0, B2l1;
    buildB(B0h0, B0l0, Wih0, Whh0, row_o0, rok0, qk8, wscale0);        // L0: [Wih0 | Whh0]
    buildB(B0h1, B0l1, Wih0, Whh0, row_o0, rok0, 32 + qk8, wscale0);
    buildB(B1h0, B1l0, nullptr, Wih1, row_o1, rok1, qk8, wscale1);     // L1-ih (vs h0)
    buildB(B1h1, B1l1, nullptr, Wih1, row_o1, rok1, 32 + qk8, wscale1);
    buildB(B2h0, B2l0, nullptr, Whh1, row_o1, rok1, qk8, wscale1);     // L1-hh (vs h1)
    buildB(B2h1, B2l1, nullptr, Whh1, row_o1, rok1, 32 + qk8, wscale1);
    PINB(B0h0) PINB(B0h1) PINB(B0l0) PINB(B0l1)
    PINB(B1h0) PINB(B1h1) PINB(B1l0) PINB(B1l1)
    PINB(B2h0) PINB(B2h1) PINB(B2l0) PINB(B2l1)

    // bias vectors preloaded into the MFMA C operand, log2-domain scaled
    const f32x4 C0 = {-L2E        * (bih0[0*HH + um0] + bhh0[0*HH + um0]),
                      -L2E        * (bih0[1*HH + um0] + bhh0[1*HH + um0]),
                      -2.0f * L2E * (bih0[2*HH + um0] + bhh0[2*HH + um0]),
                      -L2E        * (bih0[3*HH + um0] + bhh0[3*HH + um0])};
    const f32x4 C1 = {-L2E        * (bih1[0*HH + um1] + bhh1[0*HH + um1]),
                      -L2E        * (bih1[1*HH + um1] + bhh1[1*HH + um1]),
                      -2.0f * L2E * (bih1[2*HH + um1] + bhh1[2*HH + um1]),
                      -L2E        * (bih1[3*HH + um1] + bhh1[3*HH + um1])};
    const f32x4 Z0 = {0.f, 0.f, 0.f, 0.f};   // loop-invariant zero seed

    // ---- loop-invariant LDS addresses (parities hard-coded via x2 unroll) ----
    const int ab = n15 * PA + qk8;
    const unsigned short* ra00 = &hA0[0][ab];
    const unsigned short* ra01 = &hA0[1][ab];
    const unsigned short* ra10 = &hA1[0][ab];
    const unsigned short* ra11 = &hA1[1][ab];
    unsigned short* wh00 = &hA0[0][m * PA + 4 + u0];
    unsigned short* wh01 = &hA0[1][m * PA + 4 + u0];
    unsigned short* wh10 = &hA1[0][m * PA + 4 + u1];
    unsigned short* wh11 = &hA1[1][m * PA + 4 + u1];

    // x-wave prefetch registers (2-iter latency slack; vm never drains at barrier)
    const int xm = lane >> 2, xk = lane & 3;
    unsigned short* xw0 = &hA0[0][xm * PA + xk];
    unsigned short* xw1 = &hA0[1][xm * PA + xk];
    float xcur = 0.f, xnxt = 0.f;
    if (isX) {
        xcur = x[((size_t)(b0 + xm) * TT + 1) * FF + xk];
        xnxt = x[((size_t)(b0 + xm) * TT + 2) * FF + xk];
    }

    __syncthreads();

    // x(0) into parity-0 buffer (hi + lo planes)
    if (w == 0) {
        const float xv = x[((size_t)(b0 + xm) * TT + 0) * FF + xk];
        const unsigned short hb = f2bf(xv);
        hA0[0][xm * PA + xk]      = hb;
        hA0[0][xm * PA + 54 + xk] = f2bf(xv - bf2f(hb));
    }
    __syncthreads();

    float c0 = 0.f, c1 = 0.f;   // carried as cs = -2*L2E*c

    // pair loop: sub-iter A = timestep i (parity 0), sub-iter B = i+1 (parity 1)
    for (int i = 0; i < TT; i += 2) {
        // ---- sub A ----
        if (isX) {
            float xn1 = 0.f;
            if (i + 3 < TT) xn1 = x[((size_t)(b0 + xm) * TT + (i + 3)) * FF + xk];
            const unsigned short hb = f2bf(xcur);       // x(i+1): i+1 <= 511 always
            xw1[0]  = hb;
            xw1[54] = f2bf(xcur - bf2f(hb));
            xcur = xn1;                                  // becomes x((i+2)+1)
        }
        CSTEP(ra00, ra10, wh01, wh11, (i > 0));
        block_sync_lds();

        // ---- sub B ----
        if (isX) {
            float xn2 = 0.f;
            if (i + 4 < TT) xn2 = x[((size_t)(b0 + xm) * TT + (i + 4)) * FF + xk];
            if (i + 2 < TT) {
                const unsigned short hb = f2bf(xnxt);
                xw0[0]  = hb;
                xw0[54] = f2bf(xnxt - bf2f(hb));
            }
            xnxt = xn2;                                  // becomes x((i+2)+2)
        }
        CSTEP(ra01, ra11, wh00, wh10, true);
        block_sync_lds();
    }

    // tail: timestep TT (parity 0 read) -- L1 jobs only, results to h1f
    if (doL1) {
        const bf16x8 A0 = *(const bf16x8*)(ra00);
        const bf16x8 A1 = *(const bf16x8*)(ra00 + 32);
        const bf16x8 A4 = *(const bf16x8*)(ra10);
        const bf16x8 A5 = *(const bf16x8*)(ra10 + 32);
        f32x4 p = C1, q = Z0;
        p = MFMA(B1h0, A0, p); p = MFMA(B1h1, A1, p);
        p = MFMA(B1l0, A0, p); p = MFMA(B1l1, A1, p);
        q = MFMA(B2h0, A4, q); q = MFMA(B2h1, A5, q);
        q = MFMA(B2l0, A4, q); q = MFMA(B2l1, A5, q);
        if (uvalid1) {
            const float h = cell(p + q, c1);
            h1f[u1 * 16 + m] = h;
        }
    }
    __syncthreads();

    // ---- final FC: out[b] = fcW @ h1(T-1) + fcb ----
    if (tid < RB * FF) {
        const int r = tid >> 2, ft = tid & 3;
        float s = fcb[ft];
        #pragma unroll
        for (int j = 0; j < HH; j++) s = fmaf(fcW[ft * HH + j], h1f[j * 16 + r], s);
        out[(size_t)(b0 + r) * FF + ft] = s;
    }
}

extern "C" void kernel_launch(void* const* d_in, const int* in_sizes, int n_in,
                              void* d_out, int out_size, void* d_ws, size_t ws_size,
                              hipStream_t stream) {
    const float* x    = (const float*)d_in[0];
    const float* Wih0 = (const float*)d_in[1];
    const float* Whh0 = (const float*)d_in[2];
    const float* bih0 = (const float*)d_in[3];
    const float* bhh0 = (const float*)d_in[4];
    const float* Wih1 = (const float*)d_in[5];
    const float* Whh1 = (const float*)d_in[6];
    const float* bih1 = (const float*)d_in[7];
    const float* bhh1 = (const float*)d_in[8];
    const float* fcW  = (const float*)d_in[9];
    const float* fcb  = (const float*)d_in[10];
    float* out = (float*)d_out;

    const int B = in_sizes[0] / (TT * FF);   // 4096
    lstm_v17<<<B / RB, NTH, 0, stream>>>(x, Wih0, Whh0, bih0, bhh0,
                                         Wih1, Whh1, bih1, bhh1, fcW, fcb, out);
}